// Round 11
// baseline (168.437 us; speedup 1.0000x reference)
//
#include <hip/hip_runtime.h>

#define NN 50000
#define TOPK 32
#define IN_C 128
#define OUT_C 64
#define NEG_SLOPE 0.2f
#define BN_EPS 1e-5f

#define K1_BLOCKS (NN / 16)         // 3125
#define K2_BLOCKS (NN / 8)          // 6250

// workspace layout (floats)
#define WS_XBF   0                       // bf16 x_lin: NN*64*2B
#define WS_AI    (NN * 32)
#define WS_AJ    (WS_AI + NN)
#define WS_SUMS  (WS_AJ + NN)            // 8 replicas x 128
#define WS_WI    (WS_SUMS + 1024)        // 128
#define WS_WJ    (WS_WI + 128)           // 128

typedef __bf16 bf16x8 __attribute__((ext_vector_type(8)));
typedef float f32x4 __attribute__((ext_vector_type(4)));

__device__ inline float leaky(float a) { return a >= 0.f ? a : NEG_SLOPE * a; }
__device__ inline float bl(unsigned u) { return __uint_as_float(u << 16); }
__device__ inline float bh(unsigned u) { return __uint_as_float(u & 0xffff0000u); }

__device__ inline unsigned short f2bf(float f) {     // RNE fp32 -> bf16
    unsigned u = __float_as_uint(f);
    unsigned r = (u + 0x7fffu + ((u >> 16) & 1u)) >> 16;
    return (unsigned short)r;
}
__device__ inline bf16x8 cvt8(const float4 a, const float4 b) {  // HW RNE
    bf16x8 r;
    r[0] = (__bf16)a.x; r[1] = (__bf16)a.y; r[2] = (__bf16)a.z; r[3] = (__bf16)a.w;
    r[4] = (__bf16)b.x; r[5] = (__bf16)b.y; r[6] = (__bf16)b.z; r[7] = (__bf16)b.w;
    return r;
}
__device__ inline float dot4(const float4 a, const float4 b) {
    return fmaf(a.x, b.x, fmaf(a.y, b.y, fmaf(a.z, b.z, a.w * b.w)));
}

// async global->LDS, 16 B per lane; LDS dest = base + lane*16 (HW rule)
__device__ inline void async16(const uint4* g, uint4* l) {
    __builtin_amdgcn_global_load_lds(
        (const __attribute__((address_space(1))) void*)(const void*)g,
        (__attribute__((address_space(3))) void*)(void*)l, 16, 0, 0);
}

// K0: wi = W^T att_i, wj = W^T att_j (128 floats each) + zero BN sums.
__global__ __launch_bounds__(128) void k0_pre(
    const float* __restrict__ lin_w, const float* __restrict__ att_i,
    const float* __restrict__ att_j, float* __restrict__ wi,
    float* __restrict__ wj, float* __restrict__ sums)
{
    const int k = threadIdx.x;           // 0..127
    float si = 0.f, sj = 0.f;
#pragma unroll 8
    for (int c = 0; c < OUT_C; ++c) {
        const float w = lin_w[c * IN_C + k];
        si = fmaf(w, att_i[c], si);
        sj = fmaf(w, att_j[c], sj);
    }
    wi[k] = si;
    wj[k] = sj;
#pragma unroll
    for (int i = 0; i < 8; ++i) sums[k + i * 128] = 0.f;
}

// K1: x_lin(bf16) = x @ lin_w^T via MFMA 16x16x32_bf16. a_i/a_j computed
// by wave 0 as fp32 dots x.wi + emb.att_em (2 shuffles) -- no LDS, no
// __syncthreads, HW bf16 converts.
__global__ __launch_bounds__(256) void k1_mfma(
    const float* __restrict__ x, const float* __restrict__ emb,
    const float* __restrict__ lin_w,
    const float* __restrict__ wi, const float* __restrict__ wj,
    const float* __restrict__ att_em_i, const float* __restrict__ att_em_j,
    unsigned short* __restrict__ x_bf, float* __restrict__ a_i,
    float* __restrict__ a_j)
{
    const int tid = threadIdx.x;
    const int lane = tid & 63;
    const int wv = tid >> 6;
    const int quad = lane >> 4;
    const int nn = lane & 15;
    const int base = blockIdx.x * 16;
    const int c = wv * 16 + nn;          // this lane's output channel

    // weight B-frag
    const float* wr = lin_w + (size_t)c * IN_C + quad * 8;
    bf16x8 bfr[4];
#pragma unroll
    for (int s = 0; s < 4; ++s)
        bfr[s] = cvt8(*(const float4*)(wr + s * 32),
                      *(const float4*)(wr + s * 32 + 4));

    // x A-frag (keep fp32 copies for the a_i/a_j dot in wave 0)
    const float* xr = x + (size_t)(base + nn) * IN_C + quad * 8;
    float4 xa[4], xb[4];
#pragma unroll
    for (int s = 0; s < 4; ++s) {
        xa[s] = *(const float4*)(xr + s * 32);
        xb[s] = *(const float4*)(xr + s * 32 + 4);
    }
    bf16x8 afr[4];
#pragma unroll
    for (int s = 0; s < 4; ++s) afr[s] = cvt8(xa[s], xb[s]);

    f32x4 acc = {0.f, 0.f, 0.f, 0.f};
#pragma unroll
    for (int s = 0; s < 4; ++s)
        acc = __builtin_amdgcn_mfma_f32_16x16x32_bf16(afr[s], bfr[s], acc,
                                                      0, 0, 0);

    if (wv == 0) {                       // attention coefficients
        const float* wik = wi + quad * 8;
        const float* wjk = wj + quad * 8;
        float pi = 0.f, pj = 0.f;
#pragma unroll
        for (int s = 0; s < 4; ++s) {
            pi += dot4(xa[s], *(const float4*)(wik + s * 32));
            pi += dot4(xb[s], *(const float4*)(wik + s * 32 + 4));
            pj += dot4(xa[s], *(const float4*)(wjk + s * 32));
            pj += dot4(xb[s], *(const float4*)(wjk + s * 32 + 4));
        }
        const float4* er = (const float4*)(emb + (size_t)(base + nn) * OUT_C
                                           + quad * 16);
#pragma unroll
        for (int i = 0; i < 4; ++i) {
            const float4 e = er[i];
            pi += dot4(e, ((const float4*)att_em_i)[quad * 4 + i]);
            pj += dot4(e, ((const float4*)att_em_j)[quad * 4 + i]);
        }
        pi += __shfl_xor(pi, 16, 64); pi += __shfl_xor(pi, 32, 64);
        pj += __shfl_xor(pj, 16, 64); pj += __shfl_xor(pj, 32, 64);
        if (quad == 0) { a_i[base + nn] = pi; a_j[base + nn] = pj; }
    }

    // C/D: col(lane&15)=channel, row=quad*4+r=node
#pragma unroll
    for (int r = 0; r < 4; ++r)
        x_bf[(size_t)(base + quad * 4 + r) * OUT_C + c] = f2bf(acc[r]);
}

// K2 (frozen from round 10): one wave per block, 8 nodes per wave; all 33
// row-gathers via global_load_lds (no VGPR dest), one vmcnt(0) drain.
__global__ __launch_bounds__(64) void k2_attn(
    const int* __restrict__ src, const uint4* __restrict__ x_bf4,
    const float* __restrict__ a_j, const float* __restrict__ a_i,
    const float* __restrict__ bias, float* __restrict__ out,
    float* __restrict__ sums)
{
    __shared__ uint4 stage[33 * 64];
    __shared__ float wbuf[8][36];
    __shared__ float sb1[64][9], sb2[64][9];

    const int tid = threadIdx.x;
    const int g = tid >> 3;
    const int q = tid & 7;
    const int t = blockIdx.x * 8 + g;

    const int4* sp4 = (const int4*)(src + (size_t)t * TOPK);
    int4 s4[8];
#pragma unroll
    for (int i = 0; i < 8; ++i) s4[i] = sp4[i];
    const int4 sq = sp4[q];

#pragma unroll
    for (int i = 0; i < 8; ++i) {
        async16(x_bf4 + ((size_t)s4[i].x * 8 + q), &stage[(i * 4 + 0) * 64]);
        async16(x_bf4 + ((size_t)s4[i].y * 8 + q), &stage[(i * 4 + 1) * 64]);
        async16(x_bf4 + ((size_t)s4[i].z * 8 + q), &stage[(i * 4 + 2) * 64]);
        async16(x_bf4 + ((size_t)s4[i].w * 8 + q), &stage[(i * 4 + 3) * 64]);
    }
    async16(x_bf4 + ((size_t)t * 8 + q), &stage[32 * 64]);

    const float ai_t = a_i[t];
    float l0 = leaky(ai_t + a_j[sq.x]);
    float l1 = leaky(ai_t + a_j[sq.y]);
    float l2 = leaky(ai_t + a_j[sq.z]);
    float l3 = leaky(ai_t + a_j[sq.w]);
    const float ls = leaky(ai_t + a_j[t]);
    float mx = fmaxf(fmaxf(l0, l1), fmaxf(l2, l3));
#pragma unroll
    for (int d = 1; d < 8; d <<= 1) mx = fmaxf(mx, __shfl_xor(mx, d, 64));
    mx = fmaxf(mx, ls);
    const float e0 = __expf(l0 - mx), e1 = __expf(l1 - mx);
    const float e2 = __expf(l2 - mx), e3 = __expf(l3 - mx);
    const float es = __expf(ls - mx);
    float den = (e0 + e1) + (e2 + e3);
#pragma unroll
    for (int d = 1; d < 8; d <<= 1) den += __shfl_xor(den, d, 64);
    den += es + 1e-16f;
    const float inv = 1.f / den;

    ((float4*)&wbuf[g][q * 4])[0] =
        make_float4(e0 * inv, e1 * inv, e2 * inv, e3 * inv);
    if (q == 0) wbuf[g][32] = es * inv;
    __syncthreads();

    float4 w4[8];
#pragma unroll
    for (int i = 0; i < 8; ++i) w4[i] = ((const float4*)wbuf[g])[i];
    const float wself = wbuf[g][32];

    __builtin_amdgcn_s_waitcnt(0x0F70);   // vmcnt(0)
    __syncthreads();

    float A[8];
#pragma unroll
    for (int j = 0; j < 8; ++j) A[j] = 0.f;
#pragma unroll
    for (int e = 0; e < 33; ++e) {
        const uint4 u = stage[e * 64 + tid];
        const float w = (e < 32) ? ((const float*)&w4[e >> 2])[e & 3] : wself;
        A[0] = fmaf(w, bl(u.x), A[0]); A[1] = fmaf(w, bh(u.x), A[1]);
        A[2] = fmaf(w, bl(u.y), A[2]); A[3] = fmaf(w, bh(u.y), A[3]);
        A[4] = fmaf(w, bl(u.z), A[4]); A[5] = fmaf(w, bh(u.z), A[5]);
        A[6] = fmaf(w, bl(u.w), A[6]); A[7] = fmaf(w, bh(u.w), A[7]);
    }
    const float4 b0 = ((const float4*)bias)[q * 2];
    const float4 b1 = ((const float4*)bias)[q * 2 + 1];
    float v[8];
    v[0] = A[0] + b0.x; v[1] = A[1] + b0.y; v[2] = A[2] + b0.z; v[3] = A[3] + b0.w;
    v[4] = A[4] + b1.x; v[5] = A[5] + b1.y; v[6] = A[6] + b1.z; v[7] = A[7] + b1.w;
    float4* o4 = (float4*)(out + (size_t)t * OUT_C + q * 8);
    o4[0] = make_float4(v[0], v[1], v[2], v[3]);
    o4[1] = make_float4(v[4], v[5], v[6], v[7]);

#pragma unroll
    for (int j = 0; j < 8; ++j) {
        sb1[q * 8 + j][g] = v[j];
        sb2[q * 8 + j][g] = v[j] * v[j];
    }
    __syncthreads();
    {
        float t1 = 0.f, t2 = 0.f;
#pragma unroll
        for (int r = 0; r < 8; ++r) { t1 += sb1[tid][r]; t2 += sb2[tid][r]; }
        float* rep = sums + (blockIdx.x & 7) * 128;
        atomicAdd(&rep[tid], t1);
        atomicAdd(&rep[64 + tid], t2);
    }
}

// K4: BN stats from the 8 sum replicas (redundant per block), apply + ReLU.
__global__ __launch_bounds__(256) void k4_bn(
    float* __restrict__ out, const float* __restrict__ sums,
    const float* __restrict__ gamma, const float* __restrict__ beta)
{
    __shared__ float s_sc[64], s_sh[64];
    const int tid = threadIdx.x;
    if (tid < 64) {
        float s1 = 0.f, s2 = 0.f;
#pragma unroll
        for (int r = 0; r < 8; ++r) {
            s1 += sums[r * 128 + tid];
            s2 += sums[r * 128 + 64 + tid];
        }
        const float mu = s1 / (float)NN;
        const float ex2 = s2 / (float)NN;
        const float var = fmaxf(ex2 - mu * mu, 0.f);
        const float sc = gamma[tid] / sqrtf(var + BN_EPS);
        s_sc[tid] = sc;
        s_sh[tid] = beta[tid] - mu * sc;
    }
    __syncthreads();
    const int total = NN * OUT_C / 4;
    float4* p = (float4*)out;
    for (int idx = blockIdx.x * 256 + tid; idx < total; idx += gridDim.x * 256) {
        float4 v = p[idx];
        const int c0 = (idx & 15) * 4;
        v.x = fmaxf(fmaf(v.x, s_sc[c0 + 0], s_sh[c0 + 0]), 0.f);
        v.y = fmaxf(fmaf(v.y, s_sc[c0 + 1], s_sh[c0 + 1]), 0.f);
        v.z = fmaxf(fmaf(v.z, s_sc[c0 + 2], s_sh[c0 + 2]), 0.f);
        v.w = fmaxf(fmaf(v.w, s_sc[c0 + 3], s_sh[c0 + 3]), 0.f);
        p[idx] = v;
    }
}

extern "C" void kernel_launch(void* const* d_in, const int* in_sizes, int n_in,
                              void* d_out, int out_size, void* d_ws, size_t ws_size,
                              hipStream_t stream) {
    const float* x        = (const float*)d_in[0];
    const float* emb      = (const float*)d_in[1];
    const int*   edge     = (const int*)d_in[2];   // row 0 = src
    const float* lin_w    = (const float*)d_in[3];
    const float* att_i    = (const float*)d_in[4];
    const float* att_j    = (const float*)d_in[5];
    const float* att_em_i = (const float*)d_in[6];
    const float* att_em_j = (const float*)d_in[7];
    const float* bias     = (const float*)d_in[8];
    const float* gamma    = (const float*)d_in[9];
    const float* beta     = (const float*)d_in[10];

    float* ws    = (float*)d_ws;
    unsigned short* x_bf = (unsigned short*)(ws + WS_XBF);
    float* a_i   = ws + WS_AI;
    float* a_j   = ws + WS_AJ;
    float* sums  = ws + WS_SUMS;
    float* wi    = ws + WS_WI;
    float* wj    = ws + WS_WJ;
    float* out   = (float*)d_out;

    k0_pre<<<1, 128, 0, stream>>>(lin_w, att_i, att_j, wi, wj, sums);
    k1_mfma<<<K1_BLOCKS, 256, 0, stream>>>(x, emb, lin_w, wi, wj,
                                           att_em_i, att_em_j, x_bf, a_i, a_j);
    k2_attn<<<K2_BLOCKS, 64, 0, stream>>>(edge, (const uint4*)x_bf, a_j, a_i,
                                          bias, out, sums);
    k4_bn<<<1024, 256, 0, stream>>>(out, sums, gamma, beta);
}